// Round 1
// baseline (658.751 us; speedup 1.0000x reference)
//
#include <hip/hip_runtime.h>

typedef __bf16 bf16;
typedef bf16 bf16x8 __attribute__((ext_vector_type(8)));
typedef float f32x4 __attribute__((ext_vector_type(4)));

#define LD64  80   // padded LDS row stride (elems) for 64-wide tiles: 160B, 16B-aligned
#define LD128 144  // padded LDS row stride for 128-wide tiles: 288B, 16B-aligned

static __device__ __forceinline__ f32x4 mfma16(bf16x8 a, bf16x8 b, f32x4 c) {
    return __builtin_amdgcn_mfma_f32_16x16x32_bf16(a, b, c, 0, 0, 0);
}

// ---------------------------------------------------------------------------
// rel1: m = relu(emb[idx] @ W1 + b1) @ W2 + b2 ; atomicAdd into agg[idx]
// 64-row tiles, 4 waves x 16 rows, weights (64x64) transposed in LDS.
// ---------------------------------------------------------------------------
__global__ __launch_bounds__(256) void rel1_kernel(
    const float* __restrict__ emb, const int* __restrict__ idx,
    const float* __restrict__ W1, const float* __restrict__ b1,
    const float* __restrict__ W2, const float* __restrict__ b2,
    float* __restrict__ agg, int M, int numTiles)
{
    __shared__ bf16 sW1t[64 * LD64];   // [n][k]
    __shared__ bf16 sW2t[64 * LD64];
    __shared__ bf16 sG[64 * LD64];
    __shared__ bf16 sH[64 * LD64];
    __shared__ float sB1[64], sB2[64];
    __shared__ int sIdx[64];

    const int t = threadIdx.x;
    const int wave = t >> 6, lane = t & 63;
    const int l15 = lane & 15, quad = lane >> 4;

    for (int i = t; i < 64 * 64; i += 256) {
        int k = i >> 6, n = i & 63;
        sW1t[n * LD64 + k] = (bf16)W1[i];
        sW2t[n * LD64 + k] = (bf16)W2[i];
    }
    if (t < 64) { sB1[t] = b1[t]; sB2[t] = b2[t]; }

    for (int tile = blockIdx.x; tile < numTiles; tile += gridDim.x) {
        __syncthreads();  // protect sG/sIdx/sH against previous iteration readers
        const int base = tile * 64;
        {   // gather: 4 threads per row, each 16 floats
            const int r = t >> 2, p = t & 3;
            const int R = base + r;
            int id = -1;
            if (R < M) id = idx[R];
            if (p == 0) sIdx[r] = id;
            if (id >= 0) {
                const float4* src = (const float4*)(emb + (size_t)id * 64 + p * 16);
                #pragma unroll
                for (int i = 0; i < 4; ++i) {
                    float4 v = src[i];
                    int c = p * 16 + i * 4;
                    sG[r * LD64 + c + 0] = (bf16)v.x;
                    sG[r * LD64 + c + 1] = (bf16)v.y;
                    sG[r * LD64 + c + 2] = (bf16)v.z;
                    sG[r * LD64 + c + 3] = (bf16)v.w;
                }
            }
        }
        __syncthreads();

        // GEMM1: h = relu(g @ W1 + b1), wave handles rows [wave*16, wave*16+16)
        f32x4 acc[4];
        #pragma unroll
        for (int nt = 0; nt < 4; ++nt) acc[nt] = (f32x4){0.f, 0.f, 0.f, 0.f};
        #pragma unroll
        for (int kt = 0; kt < 2; ++kt) {
            bf16x8 a = *(const bf16x8*)&sG[(wave * 16 + l15) * LD64 + kt * 32 + quad * 8];
            #pragma unroll
            for (int nt = 0; nt < 4; ++nt) {
                bf16x8 bf = *(const bf16x8*)&sW1t[(nt * 16 + l15) * LD64 + kt * 32 + quad * 8];
                acc[nt] = mfma16(a, bf, acc[nt]);
            }
        }
        #pragma unroll
        for (int nt = 0; nt < 4; ++nt) {
            float bias = sB1[nt * 16 + l15];
            #pragma unroll
            for (int r = 0; r < 4; ++r) {
                float v = acc[nt][r] + bias;
                v = v > 0.f ? v : 0.f;
                sH[(wave * 16 + quad * 4 + r) * LD64 + nt * 16 + l15] = (bf16)v;
            }
        }
        __syncthreads();

        // GEMM2: m = h @ W2 + b2, then scatter
        f32x4 acc2[4];
        #pragma unroll
        for (int nt = 0; nt < 4; ++nt) acc2[nt] = (f32x4){0.f, 0.f, 0.f, 0.f};
        #pragma unroll
        for (int kt = 0; kt < 2; ++kt) {
            bf16x8 a = *(const bf16x8*)&sH[(wave * 16 + l15) * LD64 + kt * 32 + quad * 8];
            #pragma unroll
            for (int nt = 0; nt < 4; ++nt) {
                bf16x8 bf = *(const bf16x8*)&sW2t[(nt * 16 + l15) * LD64 + kt * 32 + quad * 8];
                acc2[nt] = mfma16(a, bf, acc2[nt]);
            }
        }
        #pragma unroll
        for (int nt = 0; nt < 4; ++nt) {
            float bias = sB2[nt * 16 + l15];
            #pragma unroll
            for (int r = 0; r < 4; ++r) {
                int row = wave * 16 + quad * 4 + r;
                int id = sIdx[row];
                if (id >= 0)
                    atomicAdd(&agg[(size_t)id * 64 + nt * 16 + l15], acc2[nt][r] + bias);
            }
        }
    }
}

// ---------------------------------------------------------------------------
// rel2: g = [emb[i0]||emb[i1]] (128); m = relu(g@W1+b1)@W2+b2 (128);
// cols 0..63 scatter to i0, 64..127 to i1. Waves split N (2 n-tiles each),
// B-fragments of W1/W2 held in registers.
// ---------------------------------------------------------------------------
__global__ __launch_bounds__(256) void rel2_kernel(
    const float* __restrict__ emb, const int* __restrict__ idx,  // [M][2]
    const float* __restrict__ W1, const float* __restrict__ b1,  // 128x128, 128
    const float* __restrict__ W2, const float* __restrict__ b2,
    float* __restrict__ agg, int M, int numTiles)
{
    __shared__ bf16 sG[64 * LD128];
    __shared__ bf16 sH[64 * LD128];
    __shared__ int sIdx[64 * 2];

    const int t = threadIdx.x;
    const int wave = t >> 6, lane = t & 63;
    const int l15 = lane & 15, quad = lane >> 4;

    // per-wave B fragments in registers: n-tiles {2*wave, 2*wave+1}
    bf16x8 w1f[2][4], w2f[2][4];
    float bias1[2], bias2[2];
    #pragma unroll
    for (int j = 0; j < 2; ++j) {
        const int n = (wave * 2 + j) * 16 + l15;
        bias1[j] = b1[n];
        bias2[j] = b2[n];
        #pragma unroll
        for (int kt = 0; kt < 4; ++kt) {
            bf16x8 f1, f2;
            #pragma unroll
            for (int e = 0; e < 8; ++e) {
                int k = kt * 32 + quad * 8 + e;
                f1[e] = (bf16)W1[k * 128 + n];
                f2[e] = (bf16)W2[k * 128 + n];
            }
            w1f[j][kt] = f1;
            w2f[j][kt] = f2;
        }
    }

    for (int tile = blockIdx.x; tile < numTiles; tile += gridDim.x) {
        __syncthreads();
        const int base = tile * 64;
        {   // gather: 4 threads per row, each 32 floats from one arg's emb row
            const int r = t >> 2, p = t & 3;
            const int R = base + r;
            int i0 = -1, i1 = -1;
            if (R < M) { i0 = idx[R * 2]; i1 = idx[R * 2 + 1]; }
            if (p == 0) { sIdx[r * 2] = i0; sIdx[r * 2 + 1] = i1; }
            if (R < M) {
                const int src_id = (p < 2) ? i0 : i1;
                const float4* src = (const float4*)(emb + (size_t)src_id * 64 + (p & 1) * 32);
                const int cbase = p * 32;
                #pragma unroll
                for (int i = 0; i < 8; ++i) {
                    float4 v = src[i];
                    int c = cbase + i * 4;
                    sG[r * LD128 + c + 0] = (bf16)v.x;
                    sG[r * LD128 + c + 1] = (bf16)v.y;
                    sG[r * LD128 + c + 2] = (bf16)v.z;
                    sG[r * LD128 + c + 3] = (bf16)v.w;
                }
            }
        }
        __syncthreads();

        // GEMM1 over all 4 m-tiles, this wave's 2 n-tiles
        f32x4 acc[4][2];
        #pragma unroll
        for (int mt = 0; mt < 4; ++mt)
            #pragma unroll
            for (int j = 0; j < 2; ++j) acc[mt][j] = (f32x4){0.f, 0.f, 0.f, 0.f};
        #pragma unroll
        for (int mt = 0; mt < 4; ++mt) {
            #pragma unroll
            for (int kt = 0; kt < 4; ++kt) {
                bf16x8 a = *(const bf16x8*)&sG[(mt * 16 + l15) * LD128 + kt * 32 + quad * 8];
                #pragma unroll
                for (int j = 0; j < 2; ++j) acc[mt][j] = mfma16(a, w1f[j][kt], acc[mt][j]);
            }
        }
        #pragma unroll
        for (int mt = 0; mt < 4; ++mt)
            #pragma unroll
            for (int j = 0; j < 2; ++j) {
                #pragma unroll
                for (int r = 0; r < 4; ++r) {
                    float v = acc[mt][j][r] + bias1[j];
                    v = v > 0.f ? v : 0.f;
                    sH[(mt * 16 + quad * 4 + r) * LD128 + (wave * 2 + j) * 16 + l15] = (bf16)v;
                }
            }
        __syncthreads();

        // GEMM2
        f32x4 acc2[4][2];
        #pragma unroll
        for (int mt = 0; mt < 4; ++mt)
            #pragma unroll
            for (int j = 0; j < 2; ++j) acc2[mt][j] = (f32x4){0.f, 0.f, 0.f, 0.f};
        #pragma unroll
        for (int mt = 0; mt < 4; ++mt) {
            #pragma unroll
            for (int kt = 0; kt < 4; ++kt) {
                bf16x8 a = *(const bf16x8*)&sH[(mt * 16 + l15) * LD128 + kt * 32 + quad * 8];
                #pragma unroll
                for (int j = 0; j < 2; ++j) acc2[mt][j] = mfma16(a, w2f[j][kt], acc2[mt][j]);
            }
        }
        // scatter: col<64 -> arg0 node, col>=64 -> arg1 node
        #pragma unroll
        for (int mt = 0; mt < 4; ++mt) {
            #pragma unroll
            for (int j = 0; j < 2; ++j) {
                const int col = (wave * 2 + j) * 16 + l15;
                const int sel = col >> 6;
                const int c = col & 63;
                #pragma unroll
                for (int r = 0; r < 4; ++r) {
                    int row = mt * 16 + quad * 4 + r;
                    int id = sIdx[row * 2 + sel];
                    if (id >= 0)
                        atomicAdd(&agg[(size_t)id * 64 + c], acc2[mt][j][r] + bias2[j]);
                }
            }
        }
    }
}

// ---------------------------------------------------------------------------
// update: out = relu([emb||agg] @ W1 + b1) @ W2 + b2
// ---------------------------------------------------------------------------
__global__ __launch_bounds__(256) void update_kernel(
    const float* __restrict__ emb, const float* __restrict__ agg,
    const float* __restrict__ W1, const float* __restrict__ b1,  // 128x64, 64
    const float* __restrict__ W2, const float* __restrict__ b2,  // 64x64, 64
    float* __restrict__ out, int N, int numTiles)
{
    __shared__ bf16 sW1t[64 * LD128];  // [n][k], k=128
    __shared__ bf16 sW2t[64 * LD64];   // [n][k], k=64
    __shared__ bf16 sU[64 * LD128];
    __shared__ bf16 sH[64 * LD64];
    __shared__ float sB1[64], sB2[64];

    const int t = threadIdx.x;
    const int wave = t >> 6, lane = t & 63;
    const int l15 = lane & 15, quad = lane >> 4;

    for (int i = t; i < 128 * 64; i += 256) {
        int k = i >> 6, n = i & 63;
        sW1t[n * LD128 + k] = (bf16)W1[i];
    }
    for (int i = t; i < 64 * 64; i += 256) {
        int k = i >> 6, n = i & 63;
        sW2t[n * LD64 + k] = (bf16)W2[i];
    }
    if (t < 64) { sB1[t] = b1[t]; sB2[t] = b2[t]; }

    for (int tile = blockIdx.x; tile < numTiles; tile += gridDim.x) {
        __syncthreads();
        const int base = tile * 64;
        {   // gather u = [emb row || agg row]
            const int r = t >> 2, p = t & 3;
            const int R = base + r;
            if (R < N) {
                const float* srcp = (p < 2) ? (emb + (size_t)R * 64 + p * 32)
                                            : (agg + (size_t)R * 64 + (p - 2) * 32);
                const float4* src = (const float4*)srcp;
                const int cbase = p * 32;
                #pragma unroll
                for (int i = 0; i < 8; ++i) {
                    float4 v = src[i];
                    int c = cbase + i * 4;
                    sU[r * LD128 + c + 0] = (bf16)v.x;
                    sU[r * LD128 + c + 1] = (bf16)v.y;
                    sU[r * LD128 + c + 2] = (bf16)v.z;
                    sU[r * LD128 + c + 3] = (bf16)v.w;
                }
            }
        }
        __syncthreads();

        // GEMM1: K=128 -> 4 k-steps, N=64 -> 4 n-tiles
        f32x4 acc[4];
        #pragma unroll
        for (int nt = 0; nt < 4; ++nt) acc[nt] = (f32x4){0.f, 0.f, 0.f, 0.f};
        #pragma unroll
        for (int kt = 0; kt < 4; ++kt) {
            bf16x8 a = *(const bf16x8*)&sU[(wave * 16 + l15) * LD128 + kt * 32 + quad * 8];
            #pragma unroll
            for (int nt = 0; nt < 4; ++nt) {
                bf16x8 bf = *(const bf16x8*)&sW1t[(nt * 16 + l15) * LD128 + kt * 32 + quad * 8];
                acc[nt] = mfma16(a, bf, acc[nt]);
            }
        }
        #pragma unroll
        for (int nt = 0; nt < 4; ++nt) {
            float bias = sB1[nt * 16 + l15];
            #pragma unroll
            for (int r = 0; r < 4; ++r) {
                float v = acc[nt][r] + bias;
                v = v > 0.f ? v : 0.f;
                sH[(wave * 16 + quad * 4 + r) * LD64 + nt * 16 + l15] = (bf16)v;
            }
        }
        __syncthreads();

        // GEMM2: K=64
        f32x4 acc2[4];
        #pragma unroll
        for (int nt = 0; nt < 4; ++nt) acc2[nt] = (f32x4){0.f, 0.f, 0.f, 0.f};
        #pragma unroll
        for (int kt = 0; kt < 2; ++kt) {
            bf16x8 a = *(const bf16x8*)&sH[(wave * 16 + l15) * LD64 + kt * 32 + quad * 8];
            #pragma unroll
            for (int nt = 0; nt < 4; ++nt) {
                bf16x8 bf = *(const bf16x8*)&sW2t[(nt * 16 + l15) * LD64 + kt * 32 + quad * 8];
                acc2[nt] = mfma16(a, bf, acc2[nt]);
            }
        }
        #pragma unroll
        for (int nt = 0; nt < 4; ++nt) {
            float bias = sB2[nt * 16 + l15];
            #pragma unroll
            for (int r = 0; r < 4; ++r) {
                int row = wave * 16 + quad * 4 + r;
                int R = base + row;
                if (R < N)
                    out[(size_t)R * 64 + nt * 16 + l15] = acc2[nt][r] + bias;
            }
        }
    }
}

extern "C" void kernel_launch(void* const* d_in, const int* in_sizes, int n_in,
                              void* d_out, int out_size, void* d_ws, size_t ws_size,
                              hipStream_t stream) {
    const float* emb    = (const float*)d_in[0];
    const int*   rel1   = (const int*)d_in[1];
    const int*   rel2   = (const int*)d_in[2];
    const float* m1W1   = (const float*)d_in[3];
    const float* m1b1   = (const float*)d_in[4];
    const float* m1W2   = (const float*)d_in[5];
    const float* m1b2   = (const float*)d_in[6];
    const float* m2W1   = (const float*)d_in[7];
    const float* m2b1   = (const float*)d_in[8];
    const float* m2W2   = (const float*)d_in[9];
    const float* m2b2   = (const float*)d_in[10];
    const float* uW1    = (const float*)d_in[11];
    const float* ub1    = (const float*)d_in[12];
    const float* uW2    = (const float*)d_in[13];
    const float* ub2    = (const float*)d_in[14];

    const int N  = in_sizes[0] / 64;   // 100000
    const int M1 = in_sizes[1];        // 500000
    const int M2 = in_sizes[2] / 2;    // 1000000
    float* agg = (float*)d_ws;         // [N][64]

    hipMemsetAsync(agg, 0, (size_t)N * 64 * sizeof(float), stream);

    const int t1 = (M1 + 63) / 64;
    const int g1 = t1 < 1024 ? t1 : 1024;
    rel1_kernel<<<g1, 256, 0, stream>>>(emb, rel1, m1W1, m1b1, m1W2, m1b2, agg, M1, t1);

    const int t2 = (M2 + 63) / 64;
    const int g2 = t2 < 2048 ? t2 : 2048;
    rel2_kernel<<<g2, 256, 0, stream>>>(emb, rel2, m2W1, m2b1, m2W2, m2b2, agg, M2, t2);

    const int tu = (N + 63) / 64;
    update_kernel<<<tu, 256, 0, stream>>>(emb, agg, uW1, ub1, uW2, ub2, (float*)d_out, N, tu);
}